// Round 5
// baseline (522.260 us; speedup 1.0000x reference)
//
#include <hip/hip_runtime.h>
#include <hip/hip_bf16.h>

#define DEVI __device__ __forceinline__

typedef __attribute__((ext_vector_type(8))) __bf16 bf16x8;
typedef __attribute__((ext_vector_type(4))) float f32x4;

DEVI f32x4 mfma_16x16x32(bf16x8 a, bf16x8 b, f32x4 c) {
  return __builtin_amdgcn_mfma_f32_16x16x32_bf16(a, b, c, 0, 0, 0);
}

// async global->LDS, 16B per lane; LDS dest = wave-uniform base + lane*16
DEVI void gld16(const void* g, void* l) {
  __builtin_amdgcn_global_load_lds(
      reinterpret_cast<const __attribute__((address_space(1))) unsigned int*>(
          reinterpret_cast<unsigned long long>(g)),
      reinterpret_cast<__attribute__((address_space(3))) unsigned int*>(
          reinterpret_cast<unsigned long long>(l)),
      16, 0, 0);
}

DEVI unsigned short f2bf(float f) {
  unsigned u = __builtin_bit_cast(unsigned, f);
  u += 0x7FFFu + ((u >> 16) & 1u);   // RNE
  return (unsigned short)(u >> 16);
}
DEVI float bf2f(unsigned short b) {
  return __builtin_bit_cast(float, (unsigned)b << 16);
}

// ---------------- fused fp32 -> bf16 conversion (all 5 tensors, 1 launch) ----------------
// wqkv layout: rows 0-4095 = Wq, 4096-5119 = Wk, 5120-6143 = Wv  (all [.][4096])
struct Conv5 {
  const float4 *x, *wq, *wk, *wv, *wo;
  ushort4 *xb, *wqkv, *wob;
};
__global__ void k_conv_all(Conv5 a) {
  constexpr int C0 = 2097152;            // x      2048*4096/4
  constexpr int C1 = C0 + 4194304;       // Wq     4096*4096/4
  constexpr int C2 = C1 + 1048576;       // Wk     1024*4096/4
  constexpr int C3 = C2 + 1048576;       // Wv
  constexpr int C4 = C3 + 4194304;       // Wo
  int stride = gridDim.x * blockDim.x;
  for (int i = blockIdx.x * blockDim.x + threadIdx.x; i < C4; i += stride) {
    const float4* src; ushort4* dst; int j;
    if (i < C0)      { src = a.x;  dst = a.xb;             j = i; }
    else if (i < C1) { src = a.wq; dst = a.wqkv;           j = i - C0; }
    else if (i < C2) { src = a.wk; dst = a.wqkv + 4194304; j = i - C1; }
    else if (i < C3) { src = a.wv; dst = a.wqkv + 5242880; j = i - C2; }
    else             { src = a.wo; dst = a.wob;            j = i - C3; }
    float4 v = src[j];
    ushort4 o; o.x = f2bf(v.x); o.y = f2bf(v.y); o.z = f2bf(v.z); o.w = f2bf(v.w);
    dst[j] = o;
  }
}

// ---------------- RoPE table: tab[s*64+d] = (cos, sin) of s * theta^(-d/64) ----------------
__global__ void k_rope_table(float2* __restrict__ tab) {
  int idx = blockIdx.x * blockDim.x + threadIdx.x;   // 2048*64
  int s = idx >> 6, d = idx & 63;
  float invf = powf(10000.0f, -(float)d * (1.0f / 64.0f));
  float f = (float)s * invf;
  tab[idx] = make_float2(cosf(f), sinf(f));
}

// ---------------- RoPE apply, vectorized: 8 (d,d+64) pairs per thread ----------------
template <int NH_, int L2NH>
__global__ void k_rope_v(unsigned short* __restrict__ X, const float2* __restrict__ tab,
                         const int* __restrict__ pos, float scale) {
  int t = blockIdx.x * blockDim.x + threadIdx.x;     // 2048*NH_*8 threads
  int d0 = (t & 7) * 8;
  int sh = t >> 3;
  int s  = sh >> L2NH;
  int h  = sh & (NH_ - 1);
  size_t base = (size_t)s * (NH_ * 128) + h * 128 + d0;
  const float4* tf = (const float4*)(tab + (size_t)pos[s] * 64 + d0);
  unsigned short a[8], b[8], oa[8], ob[8];
  *(ushort4*)&a[0] = *(const ushort4*)(X + base);
  *(ushort4*)&a[4] = *(const ushort4*)(X + base + 4);
  *(ushort4*)&b[0] = *(const ushort4*)(X + base + 64);
  *(ushort4*)&b[4] = *(const ushort4*)(X + base + 68);
#pragma unroll
  for (int j = 0; j < 4; ++j) {
    float4 cs = tf[j];                               // c(2j), s(2j), c(2j+1), s(2j+1)
    float x1 = bf2f(a[2*j]),   x2 = bf2f(b[2*j]);
    float y1 = bf2f(a[2*j+1]), y2 = bf2f(b[2*j+1]);
    oa[2*j]   = f2bf((x1 * cs.x - x2 * cs.y) * scale);
    ob[2*j]   = f2bf((x2 * cs.x + x1 * cs.y) * scale);
    oa[2*j+1] = f2bf((y1 * cs.z - y2 * cs.w) * scale);
    ob[2*j+1] = f2bf((y2 * cs.z + y1 * cs.w) * scale);
  }
  *(ushort4*)(X + base)      = *(ushort4*)&oa[0];
  *(ushort4*)(X + base + 4)  = *(ushort4*)&oa[4];
  *(ushort4*)(X + base + 64) = *(ushort4*)&ob[0];
  *(ushort4*)(X + base + 68) = *(ushort4*)&ob[4];
}

// ---------------- GEMM: C = A(Mx4096) * B(Nx4096)^T, BK=64, XOR-swizzled LDS ----------------
// swizzle invariant: row r, 16B-slot c holds k-chunk c ^ (r&7).
// EPI 0: split QKV epilogue (col<4096 -> Q bf16; <5120 -> K bf16; else Vt transposed bf16)
// EPI 1: f32 C[row*4096+col]
template <int EPI>
__global__ __launch_bounds__(256, 2)
void k_gemm64(const unsigned short* __restrict__ A,
              const unsigned short* __restrict__ B,
              void* __restrict__ Cp,
              unsigned short* __restrict__ Kp,
              unsigned short* __restrict__ Vtp,
              int K) {
  __shared__ __align__(16) unsigned short As[128][64];   // 16 KB
  __shared__ __align__(16) unsigned short Bs[128][64];   // 16 KB
  const int tid  = threadIdx.x;
  const int lane = tid & 63;
  const int wave = tid >> 6;
  const int bm = blockIdx.y * 128;
  const int bn = blockIdx.x * 128;
  const int wm = (wave >> 1) * 64;
  const int wn = (wave & 1) * 64;
  const int l15 = lane & 15;
  const int lg  = lane >> 4;

  f32x4 acc[4][4] = {};

  // staging: wave w owns rows [w*32, w*32+32), 4 chunks of 8 rows (128B/row).
  const int srow  = lane >> 3;                 // 0..7 (== row&7)
  const int scol  = ((lane & 7) ^ srow) * 8;   // element offset within row
  const unsigned short* aS = A + (size_t)(bm + wave * 32 + srow) * K + scol;
  const unsigned short* bS = B + (size_t)(bn + wave * 32 + srow) * K + scol;

  for (int k0 = 0; k0 < K; k0 += 64) {
    __syncthreads();
#pragma unroll
    for (int c = 0; c < 4; ++c) {
      gld16(aS + (size_t)(c * 8) * K + k0, &As[wave * 32 + c * 8][0]);
      gld16(bS + (size_t)(c * 8) * K + k0, &Bs[wave * 32 + c * 8][0]);
    }
    __syncthreads();

#pragma unroll
    for (int ks = 0; ks < 2; ++ks) {
      bf16x8 a[4], b[4];
#pragma unroll
      for (int m = 0; m < 4; ++m)
        a[m] = *(const bf16x8*)&As[wm + m * 16 + l15][((ks * 4 + lg) ^ (l15 & 7)) * 8];
#pragma unroll
      for (int n = 0; n < 4; ++n)
        b[n] = *(const bf16x8*)&Bs[wn + n * 16 + l15][((ks * 4 + lg) ^ (l15 & 7)) * 8];
#pragma unroll
      for (int m = 0; m < 4; ++m)
#pragma unroll
        for (int n = 0; n < 4; ++n)
          acc[m][n] = mfma_16x16x32(a[m], b[n], acc[m][n]);
    }
  }

#pragma unroll
  for (int m = 0; m < 4; ++m)
#pragma unroll
    for (int n = 0; n < 4; ++n)
#pragma unroll
      for (int r = 0; r < 4; ++r) {
        int row = bm + wm + m * 16 + lg * 4 + r;
        int col = bn + wn + n * 16 + l15;
        float v = acc[m][n][r];
        if (EPI == 0) {
          if (col < 4096)      ((unsigned short*)Cp)[(size_t)row * 4096 + col] = f2bf(v);
          else if (col < 5120) Kp[(size_t)row * 1024 + (col - 4096)] = f2bf(v);
          else                 Vtp[(size_t)(col - 5120) * 2048 + row] = f2bf(v);
        } else {
          ((float*)Cp)[(size_t)row * 4096 + col] = v;
        }
      }
}

// ---------------- Flash attention v5: QBLK=128 (2 row-groups/wave), shared K/V frags ----------------
// causal, GQA 32Q/8KV, HD=128, KVBLK=64, double-buffered, XOR-swizzled LDS (K, V, and P).
// S^T = mfma(K,Q): lane (lg,l15) holds S^T[kv0+n*16+lg*4+r][q=l15] -> per-lane softmax.
// O^T = mfma(Vt,P): lane holds O^T[d=j*16+lg*4+r][q=l15]; transposed out via LDS.
// grid: 512 blocks (16 q-blocks x 32 heads), heavy q first; wave w owns rows
// {q0+w*16..+15} (g=0) and {q0+64+w*16..+15} (g=1). K/V fragments shared by both groups.
__global__ __launch_bounds__(256, 2)
void k_attn(const unsigned short* __restrict__ Q,    // [2048][4096], pre-scaled
            const unsigned short* __restrict__ Kb,   // [2048][1024]
            const unsigned short* __restrict__ Vt,   // [1024][2048]  (d-major)
            unsigned short* __restrict__ AO) {       // [2048][4096]
  __shared__ __align__(16) unsigned short Kl[2][64][128];  // 32 KB (epilogue scratch g0)
  __shared__ __align__(16) unsigned short Vl[2][128][64];  // 32 KB (epilogue scratch g1)
  __shared__ __align__(16) unsigned short Pl[4][2][16][64];// 16 KB, 16B-chunk XOR swizzle
  const int tid = threadIdx.x, lane = tid & 63, w = tid >> 6;
  const int bid = blockIdx.x;
  const int qi = 15 - (bid >> 5);            // heavy blocks dispatched first
  const int h  = bid & 31;
  const int q0 = qi * 128;
  const int kh = h >> 2;
  const int l15 = lane & 15, lg = lane >> 4;
  const int swz = (l15 & 7);

  bf16x8 qf0[4], qf1[4];
  {
    const unsigned short* qr0 = Q + (size_t)(q0 + w * 16 + l15) * 4096 + h * 128;
    const unsigned short* qr1 = qr0 + (size_t)64 * 4096;
#pragma unroll
    for (int ks = 0; ks < 4; ++ks) {
      qf0[ks] = *(const bf16x8*)(qr0 + ks * 32 + lg * 8);
      qf1[ks] = *(const bf16x8*)(qr1 + ks * 32 + lg * 8);
    }
  }

  f32x4 o0[8] = {}, o1[8] = {};
  float m0 = -1e30f, l0 = 0.f, m1 = -1e30f, l1 = 0.f;
  const int nkb  = 2 * qi + 2;
  const int myq0 = q0 + w * 16 + l15;
  const int myq1 = myq0 + 64;

  auto stageK = [&](int buf, int kv0) {
#pragma unroll
    for (int c = 0; c < 4; ++c) {
      int row = 16 * w + 4 * c + lg;
      gld16(Kb + (size_t)(kv0 + row) * 1024 + kh * 128 + ((l15 ^ (row & 7)) * 8),
            &Kl[buf][16 * w + 4 * c][0]);
    }
  };
  auto stageV = [&](int buf, int kv0) {
#pragma unroll
    for (int c = 0; c < 4; ++c) {
      int row = 32 * w + 8 * c + (lane >> 3);
      gld16(Vt + (size_t)(kh * 128 + row) * 2048 + kv0 + (((lane & 7) ^ (row & 7)) * 8),
            &Vl[buf][32 * w + 8 * c][0]);
    }
  };

  stageK(0, 0);
  stageV(0, 0);
  int cur = 0;

  for (int kb = 0; kb < nkb; ++kb) {
    const int kv0 = kb * 64;
    __syncthreads();                         // buf[cur] staged; buf[cur^1] free
    if (kb + 1 < nkb) { stageK(cur ^ 1, kv0 + 64); stageV(cur ^ 1, kv0 + 64); }

    const bool skip0 = (kb == nkb - 1);      // last tile: g0 rows fully masked
    const bool maskt = (kb >= nkb - 2);      // diagonal region

    // S^T = K Q^T for both row-groups, sharing the K fragments
    f32x4 s0[4] = {}, s1[4] = {};
    __builtin_amdgcn_s_setprio(1);
#pragma unroll
    for (int ks = 0; ks < 4; ++ks)
#pragma unroll
      for (int n = 0; n < 4; ++n) {
        bf16x8 bk = *(const bf16x8*)&Kl[cur][n * 16 + l15][((ks * 4 + lg) ^ swz) * 8];
        if (!skip0) s0[n] = mfma_16x16x32(bk, qf0[ks], s0[n]);
        s1[n] = mfma_16x16x32(bk, qf1[ks], s1[n]);
      }
    __builtin_amdgcn_s_setprio(0);

    if (maskt) {
#pragma unroll
      for (int n = 0; n < 4; ++n)
#pragma unroll
        for (int r = 0; r < 4; ++r) {
          int kv = kv0 + n * 16 + lg * 4 + r;
          if (!skip0 && kv > myq0) s0[n][r] = -1e30f;
          if (kv > myq1)           s1[n][r] = -1e30f;
        }
    }

    // per-lane online softmax (16 scores/lane), T13 defer-rescale, per group
    if (!skip0) {
      float mx = -1e30f;
#pragma unroll
      for (int n = 0; n < 4; ++n)
        mx = fmaxf(mx, fmaxf(fmaxf(s0[n][0], s0[n][1]), fmaxf(s0[n][2], s0[n][3])));
      mx = fmaxf(mx, __shfl_xor(mx, 16));
      mx = fmaxf(mx, __shfl_xor(mx, 32));
      if (!__all(mx <= m0 + 8.0f)) {
        float mn = fmaxf(m0, mx);
        float fac = __expf(m0 - mn);
        m0 = mn; l0 *= fac;
#pragma unroll
        for (int j = 0; j < 8; ++j) {
          o0[j][0] *= fac; o0[j][1] *= fac; o0[j][2] *= fac; o0[j][3] *= fac;
        }
      }
      float rs = 0.f;
#pragma unroll
      for (int n = 0; n < 4; ++n)
#pragma unroll
        for (int r = 0; r < 4; ++r) {
          float pv = __expf(s0[n][r] - m0);
          s0[n][r] = pv; rs += pv;
        }
      rs += __shfl_xor(rs, 16);
      rs += __shfl_xor(rs, 32);
      l0 += rs;
#pragma unroll
      for (int n = 0; n < 4; ++n) {          // P write, 16B-chunk swizzled
        ushort4 pk;
        pk.x = f2bf(s0[n][0]); pk.y = f2bf(s0[n][1]);
        pk.z = f2bf(s0[n][2]); pk.w = f2bf(s0[n][3]);
        *(ushort4*)&Pl[w][0][l15][(((2 * n + (lg >> 1)) ^ swz) << 3) + ((lg & 1) << 2)] = pk;
      }
    }
    {
      float mx = -1e30f;
#pragma unroll
      for (int n = 0; n < 4; ++n)
        mx = fmaxf(mx, fmaxf(fmaxf(s1[n][0], s1[n][1]), fmaxf(s1[n][2], s1[n][3])));
      mx = fmaxf(mx, __shfl_xor(mx, 16));
      mx = fmaxf(mx, __shfl_xor(mx, 32));
      if (!__all(mx <= m1 + 8.0f)) {
        float mn = fmaxf(m1, mx);
        float fac = __expf(m1 - mn);
        m1 = mn; l1 *= fac;
#pragma unroll
        for (int j = 0; j < 8; ++j) {
          o1[j][0] *= fac; o1[j][1] *= fac; o1[j][2] *= fac; o1[j][3] *= fac;
        }
      }
      float rs = 0.f;
#pragma unroll
      for (int n = 0; n < 4; ++n)
#pragma unroll
        for (int r = 0; r < 4; ++r) {
          float pv = __expf(s1[n][r] - m1);
          s1[n][r] = pv; rs += pv;
        }
      rs += __shfl_xor(rs, 16);
      rs += __shfl_xor(rs, 32);
      l1 += rs;
#pragma unroll
      for (int n = 0; n < 4; ++n) {
        ushort4 pk;
        pk.x = f2bf(s1[n][0]); pk.y = f2bf(s1[n][1]);
        pk.z = f2bf(s1[n][2]); pk.w = f2bf(s1[n][3]);
        *(ushort4*)&Pl[w][1][l15][(((2 * n + (lg >> 1)) ^ swz) << 3) + ((lg & 1) << 2)] = pk;
      }
    }
    asm volatile("s_waitcnt lgkmcnt(0)" ::: "memory");

    bf16x8 pa00, pa01;
    if (!skip0) {
      pa00 = *(const bf16x8*)&Pl[w][0][l15][(lg ^ swz) << 3];
      pa01 = *(const bf16x8*)&Pl[w][0][l15][((4 + lg) ^ swz) << 3];
    }
    bf16x8 pa10 = *(const bf16x8*)&Pl[w][1][l15][(lg ^ swz) << 3];
    bf16x8 pa11 = *(const bf16x8*)&Pl[w][1][l15][((4 + lg) ^ swz) << 3];

    // O^T += V^T P^T, V fragments shared by both groups
    __builtin_amdgcn_s_setprio(1);
#pragma unroll
    for (int j = 0; j < 8; ++j) {
      bf16x8 bv0 = *(const bf16x8*)&Vl[cur][j * 16 + l15][(lg ^ swz) * 8];
      bf16x8 bv1 = *(const bf16x8*)&Vl[cur][j * 16 + l15][((4 + lg) ^ swz) * 8];
      if (!skip0) {
        o0[j] = mfma_16x16x32(bv0, pa00, o0[j]);
        o0[j] = mfma_16x16x32(bv1, pa01, o0[j]);
      }
      o1[j] = mfma_16x16x32(bv0, pa10, o1[j]);
      o1[j] = mfma_16x16x32(bv1, pa11, o1[j]);
    }
    __builtin_amdgcn_s_setprio(0);
    cur ^= 1;
  }

  // epilogue: normalize, transpose O^T -> O via LDS (Kl for g0, Vl for g1), coalesced store
  float inv0 = 1.0f / l0, inv1 = 1.0f / l1;
  __syncthreads();                           // all waves done with Kl/Vl tiles
  unsigned short* O0 = &Kl[0][0][0];         // per-wave slot: [16][136]
  unsigned short* O1 = &Vl[0][0][0];
#pragma unroll
  for (int j = 0; j < 8; ++j) {
    ushort4 t0, t1;
    t0.x = f2bf(o0[j][0] * inv0); t0.y = f2bf(o0[j][1] * inv0);
    t0.z = f2bf(o0[j][2] * inv0); t0.w = f2bf(o0[j][3] * inv0);
    t1.x = f2bf(o1[j][0] * inv1); t1.y = f2bf(o1[j][1] * inv1);
    t1.z = f2bf(o1[j][2] * inv1); t1.w = f2bf(o1[j][3] * inv1);
    *(ushort4*)&O0[w * 2176 + l15 * 136 + j * 16 + lg * 4] = t0;
    *(ushort4*)&O1[w * 2176 + l15 * 136 + j * 16 + lg * 4] = t1;
  }
  asm volatile("s_waitcnt lgkmcnt(0)" ::: "memory");
#pragma unroll
  for (int p = 0; p < 4; ++p) {
    int row = p * 4 + lg;
    bf16x8 v0 = *(const bf16x8*)&O0[w * 2176 + row * 136 + l15 * 8];
    bf16x8 v1 = *(const bf16x8*)&O1[w * 2176 + row * 136 + l15 * 8];
    *(bf16x8*)(AO + (size_t)(q0 + w * 16 + row) * 4096 + h * 128 + l15 * 8) = v0;
    *(bf16x8*)(AO + (size_t)(q0 + 64 + w * 16 + row) * 4096 + h * 128 + l15 * 8) = v1;
  }
}

// ---------------- launch ----------------
extern "C" void kernel_launch(void* const* d_in, const int* in_sizes, int n_in,
                              void* d_out, int out_size, void* d_ws, size_t ws_size,
                              hipStream_t stream) {
  const float* x  = (const float*)d_in[0];
  const float* Wq = (const float*)d_in[1];
  const float* Wk = (const float*)d_in[2];
  const float* Wv = (const float*)d_in[3];
  const float* Wo = (const float*)d_in[4];
  const int*   pos = (const int*)d_in[5];
  float* out = (float*)d_out;

  char* p = (char*)d_ws;
  unsigned short* xb   = (unsigned short*)p; p += (size_t)2048 * 4096 * 2;
  unsigned short* wqkv = (unsigned short*)p; p += (size_t)6144 * 4096 * 2;  // Wq,Wk,Wv rows
  unsigned short* wob  = (unsigned short*)p; p += (size_t)4096 * 4096 * 2;
  unsigned short* qb   = (unsigned short*)p; p += (size_t)2048 * 4096 * 2;
  unsigned short* kb   = (unsigned short*)p; p += (size_t)2048 * 1024 * 2;
  unsigned short* vtb  = (unsigned short*)p; p += (size_t)1024 * 2048 * 2;
  unsigned short* aob  = (unsigned short*)p; p += (size_t)2048 * 4096 * 2;
  float2*         tab  = (float2*)p;         p += (size_t)2048 * 64 * 8;

  Conv5 ca;
  ca.x  = (const float4*)x;  ca.wq = (const float4*)Wq; ca.wk = (const float4*)Wk;
  ca.wv = (const float4*)Wv; ca.wo = (const float4*)Wo;
  ca.xb = (ushort4*)xb; ca.wqkv = (ushort4*)wqkv; ca.wob = (ushort4*)wob;
  k_conv_all<<<4096, 256, 0, stream>>>(ca);
  k_rope_table<<<512, 256, 0, stream>>>(tab);

  // merged QKV projection: C[2048][6144] split into qb / kb / vtb^T
  k_gemm64<0><<<dim3(48, 16), 256, 0, stream>>>(xb, wqkv, qb, kb, vtb, 4096);

  const float scale = 0.08838834764831845f;  // 1/sqrt(128), folded into Q
  k_rope_v<32, 5><<<2048, 256, 0, stream>>>(qb, tab, pos, scale);
  k_rope_v<8, 3><<<512, 256, 0, stream>>>(kb, tab, pos, 1.0f);

  k_attn<<<512, 256, 0, stream>>>(qb, kb, vtb, aob);

  k_gemm64<1><<<dim3(32, 16), 256, 0, stream>>>(aob, wob, out, nullptr, nullptr, 4096);
}

// Round 6
// 510.053 us; speedup vs baseline: 1.0239x; 1.0239x over previous
//
#include <hip/hip_runtime.h>
#include <hip/hip_bf16.h>

#define DEVI __device__ __forceinline__

typedef __attribute__((ext_vector_type(8))) __bf16 bf16x8;
typedef __attribute__((ext_vector_type(4))) float f32x4;

DEVI f32x4 mfma_16x16x32(bf16x8 a, bf16x8 b, f32x4 c) {
  return __builtin_amdgcn_mfma_f32_16x16x32_bf16(a, b, c, 0, 0, 0);
}

// async global->LDS, 16B per lane; LDS dest = wave-uniform base + lane*16
DEVI void gld16(const void* g, void* l) {
  __builtin_amdgcn_global_load_lds(
      reinterpret_cast<const __attribute__((address_space(1))) unsigned int*>(
          reinterpret_cast<unsigned long long>(g)),
      reinterpret_cast<__attribute__((address_space(3))) unsigned int*>(
          reinterpret_cast<unsigned long long>(l)),
      16, 0, 0);
}

DEVI unsigned short f2bf(float f) {
  unsigned u = __builtin_bit_cast(unsigned, f);
  u += 0x7FFFu + ((u >> 16) & 1u);   // RNE
  return (unsigned short)(u >> 16);
}
DEVI unsigned short f2bf_trunc(float f) {            // cheap pack for P (values >= 0)
  return (unsigned short)(__builtin_bit_cast(unsigned, f) >> 16);
}
DEVI float bf2f(unsigned short b) {
  return __builtin_bit_cast(float, (unsigned)b << 16);
}

// ---------------- fused fp32 -> bf16 conversion (all 5 tensors, 1 launch) ----------------
// wqkv layout: rows 0-4095 = Wq, 4096-5119 = Wk, 5120-6143 = Wv  (all [.][4096])
struct Conv5 {
  const float4 *x, *wq, *wk, *wv, *wo;
  ushort4 *xb, *wqkv, *wob;
};
__global__ void k_conv_all(Conv5 a) {
  constexpr int C0 = 2097152;            // x      2048*4096/4
  constexpr int C1 = C0 + 4194304;       // Wq     4096*4096/4
  constexpr int C2 = C1 + 1048576;       // Wk     1024*4096/4
  constexpr int C3 = C2 + 1048576;       // Wv
  constexpr int C4 = C3 + 4194304;       // Wo
  int stride = gridDim.x * blockDim.x;
  for (int i = blockIdx.x * blockDim.x + threadIdx.x; i < C4; i += stride) {
    const float4* src; ushort4* dst; int j;
    if (i < C0)      { src = a.x;  dst = a.xb;             j = i; }
    else if (i < C1) { src = a.wq; dst = a.wqkv;           j = i - C0; }
    else if (i < C2) { src = a.wk; dst = a.wqkv + 4194304; j = i - C1; }
    else if (i < C3) { src = a.wv; dst = a.wqkv + 5242880; j = i - C2; }
    else             { src = a.wo; dst = a.wob;            j = i - C3; }
    float4 v = src[j];
    ushort4 o; o.x = f2bf(v.x); o.y = f2bf(v.y); o.z = f2bf(v.z); o.w = f2bf(v.w);
    dst[j] = o;
  }
}

// ---------------- RoPE table: tab[s*64+d] = (cos, sin) of s * theta^(-d/64) ----------------
__global__ void k_rope_table(float2* __restrict__ tab) {
  int idx = blockIdx.x * blockDim.x + threadIdx.x;   // 2048*64
  int s = idx >> 6, d = idx & 63;
  float invf = powf(10000.0f, -(float)d * (1.0f / 64.0f));
  float f = (float)s * invf;
  tab[idx] = make_float2(cosf(f), sinf(f));
}

// ---------------- RoPE apply, vectorized: 8 (d,d+64) pairs per thread ----------------
template <int NH_, int L2NH>
__global__ void k_rope_v(unsigned short* __restrict__ X, const float2* __restrict__ tab,
                         const int* __restrict__ pos, float scale) {
  int t = blockIdx.x * blockDim.x + threadIdx.x;     // 2048*NH_*8 threads
  int d0 = (t & 7) * 8;
  int sh = t >> 3;
  int s  = sh >> L2NH;
  int h  = sh & (NH_ - 1);
  size_t base = (size_t)s * (NH_ * 128) + h * 128 + d0;
  const float4* tf = (const float4*)(tab + (size_t)pos[s] * 64 + d0);
  unsigned short a[8], b[8], oa[8], ob[8];
  *(ushort4*)&a[0] = *(const ushort4*)(X + base);
  *(ushort4*)&a[4] = *(const ushort4*)(X + base + 4);
  *(ushort4*)&b[0] = *(const ushort4*)(X + base + 64);
  *(ushort4*)&b[4] = *(const ushort4*)(X + base + 68);
#pragma unroll
  for (int j = 0; j < 4; ++j) {
    float4 cs = tf[j];                               // c(2j), s(2j), c(2j+1), s(2j+1)
    float x1 = bf2f(a[2*j]),   x2 = bf2f(b[2*j]);
    float y1 = bf2f(a[2*j+1]), y2 = bf2f(b[2*j+1]);
    oa[2*j]   = f2bf((x1 * cs.x - x2 * cs.y) * scale);
    ob[2*j]   = f2bf((x2 * cs.x + x1 * cs.y) * scale);
    oa[2*j+1] = f2bf((y1 * cs.z - y2 * cs.w) * scale);
    ob[2*j+1] = f2bf((y2 * cs.z + y1 * cs.w) * scale);
  }
  *(ushort4*)(X + base)      = *(ushort4*)&oa[0];
  *(ushort4*)(X + base + 4)  = *(ushort4*)&oa[4];
  *(ushort4*)(X + base + 64) = *(ushort4*)&ob[0];
  *(ushort4*)(X + base + 68) = *(ushort4*)&ob[4];
}

// ---------------- GEMM: C = A(Mx4096) * B(Nx4096)^T, BK=64, XOR-swizzled LDS ----------------
// swizzle invariant: row r, 16B-slot c holds k-chunk c ^ (r&7).
// EPI 0: split QKV epilogue (col<4096 -> Q bf16; <5120 -> K bf16; else Vt transposed bf16)
// EPI 1: f32 C[row*4096+col]
template <int EPI>
__global__ __launch_bounds__(256, 2)
void k_gemm64(const unsigned short* __restrict__ A,
              const unsigned short* __restrict__ B,
              void* __restrict__ Cp,
              unsigned short* __restrict__ Kp,
              unsigned short* __restrict__ Vtp,
              int K) {
  __shared__ __align__(16) unsigned short As[128][64];   // 16 KB
  __shared__ __align__(16) unsigned short Bs[128][64];   // 16 KB
  const int tid  = threadIdx.x;
  const int lane = tid & 63;
  const int wave = tid >> 6;
  const int bm = blockIdx.y * 128;
  const int bn = blockIdx.x * 128;
  const int wm = (wave >> 1) * 64;
  const int wn = (wave & 1) * 64;
  const int l15 = lane & 15;
  const int lg  = lane >> 4;

  f32x4 acc[4][4] = {};

  // staging: wave w owns rows [w*32, w*32+32), 4 chunks of 8 rows (128B/row).
  const int srow  = lane >> 3;                 // 0..7 (== row&7)
  const int scol  = ((lane & 7) ^ srow) * 8;   // element offset within row
  const unsigned short* aS = A + (size_t)(bm + wave * 32 + srow) * K + scol;
  const unsigned short* bS = B + (size_t)(bn + wave * 32 + srow) * K + scol;

  for (int k0 = 0; k0 < K; k0 += 64) {
    __syncthreads();
#pragma unroll
    for (int c = 0; c < 4; ++c) {
      gld16(aS + (size_t)(c * 8) * K + k0, &As[wave * 32 + c * 8][0]);
      gld16(bS + (size_t)(c * 8) * K + k0, &Bs[wave * 32 + c * 8][0]);
    }
    __syncthreads();

#pragma unroll
    for (int ks = 0; ks < 2; ++ks) {
      bf16x8 a[4], b[4];
#pragma unroll
      for (int m = 0; m < 4; ++m)
        a[m] = *(const bf16x8*)&As[wm + m * 16 + l15][((ks * 4 + lg) ^ (l15 & 7)) * 8];
#pragma unroll
      for (int n = 0; n < 4; ++n)
        b[n] = *(const bf16x8*)&Bs[wn + n * 16 + l15][((ks * 4 + lg) ^ (l15 & 7)) * 8];
#pragma unroll
      for (int m = 0; m < 4; ++m)
#pragma unroll
        for (int n = 0; n < 4; ++n)
          acc[m][n] = mfma_16x16x32(a[m], b[n], acc[m][n]);
    }
  }

#pragma unroll
  for (int m = 0; m < 4; ++m)
#pragma unroll
    for (int n = 0; n < 4; ++n)
#pragma unroll
      for (int r = 0; r < 4; ++r) {
        int row = bm + wm + m * 16 + lg * 4 + r;
        int col = bn + wn + n * 16 + l15;
        float v = acc[m][n][r];
        if (EPI == 0) {
          if (col < 4096)      ((unsigned short*)Cp)[(size_t)row * 4096 + col] = f2bf(v);
          else if (col < 5120) Kp[(size_t)row * 1024 + (col - 4096)] = f2bf(v);
          else                 Vtp[(size_t)(col - 5120) * 2048 + row] = f2bf(v);
        } else {
          ((float*)Cp)[(size_t)row * 4096 + col] = v;
        }
      }
}

// ---------------- Flash attention v6: complementary q-block pairing ----------------
// causal, GQA 32Q/8KV, HD=128, KVBLK=64, double-buffered, XOR-swizzled LDS (K, V, P).
// Block (qi,h) owns q-rows lq0=qi*64 (g0) and hq0=(31-qi)*64 (g1).
//   shared phase kb<qi+1: both groups consume the staged tile (K/V frags shared)
//   solo phase: g1 only.  Per-block work = 2(qi+1) + (31-2qi) = 33 units for ALL qi.
// Softmax in log2 domain (Q pre-scaled by 1/sqrt(128)*log2e), exp2f, defer-rescale.
// S^T = mfma(K,Q): lane (lg,l15) holds S^T[kv0+n*16+lg*4+r][q=l15] -> per-lane softmax.
// O^T = mfma(Vt,P): lane holds O^T[d=j*16+lg*4+r][q=l15]; transposed out via LDS.
__global__ __launch_bounds__(256, 2)
void k_attn(const unsigned short* __restrict__ Q,    // [2048][4096], pre-scaled
            const unsigned short* __restrict__ Kb,   // [2048][1024]
            const unsigned short* __restrict__ Vt,   // [1024][2048]  (d-major)
            unsigned short* __restrict__ AO) {       // [2048][4096]
  __shared__ __align__(16) unsigned short Kl[2][64][128];  // 32 KB (epilogue scratch g0)
  __shared__ __align__(16) unsigned short Vl[2][128][64];  // 32 KB (epilogue scratch g1)
  __shared__ __align__(16) unsigned short Pl[4][2][16][64];// 16 KB, 16B-chunk XOR swizzle
  const int tid = threadIdx.x, lane = tid & 63, w = tid >> 6;
  const int bid = blockIdx.x;
  const int qi = bid >> 5;                   // 0..15
  const int h  = bid & 31;
  const int lq0 = qi * 64;
  const int hq0 = (31 - qi) * 64;
  const int lo_nkb = qi + 1;
  const int hi_nkb = 32 - qi;
  const int kh = h >> 2;
  const int l15 = lane & 15, lg = lane >> 4;
  const int swz = (l15 & 7);

  bf16x8 qf0[4], qf1[4];
  {
    const unsigned short* qr0 = Q + (size_t)(lq0 + w * 16 + l15) * 4096 + h * 128;
    const unsigned short* qr1 = Q + (size_t)(hq0 + w * 16 + l15) * 4096 + h * 128;
#pragma unroll
    for (int ks = 0; ks < 4; ++ks) {
      qf0[ks] = *(const bf16x8*)(qr0 + ks * 32 + lg * 8);
      qf1[ks] = *(const bf16x8*)(qr1 + ks * 32 + lg * 8);
    }
  }

  f32x4 o0[8] = {}, o1[8] = {};
  float m0 = -1e30f, l0 = 0.f, m1 = -1e30f, l1 = 0.f;
  const int myq0 = lq0 + w * 16 + l15;
  const int myq1 = hq0 + w * 16 + l15;

  auto stageK = [&](int buf, int kv0) {
#pragma unroll
    for (int c = 0; c < 4; ++c) {
      int row = 16 * w + 4 * c + lg;
      gld16(Kb + (size_t)(kv0 + row) * 1024 + kh * 128 + ((l15 ^ (row & 7)) * 8),
            &Kl[buf][16 * w + 4 * c][0]);
    }
  };
  auto stageV = [&](int buf, int kv0) {
#pragma unroll
    for (int c = 0; c < 4; ++c) {
      int row = 32 * w + 8 * c + (lane >> 3);
      gld16(Vt + (size_t)(kh * 128 + row) * 2048 + kv0 + (((lane & 7) ^ (row & 7)) * 8),
            &Vl[buf][32 * w + 8 * c][0]);
    }
  };

  stageK(0, 0);
  stageV(0, 0);
  int cur = 0;

  for (int kb = 0; kb < hi_nkb; ++kb) {
    const int kv0 = kb * 64;
    __syncthreads();                         // buf[cur] staged; buf[cur^1] free
    if (kb + 1 < hi_nkb) { stageK(cur ^ 1, kv0 + 64); stageV(cur ^ 1, kv0 + 64); }

    const bool act0  = (kb < lo_nkb);        // g0 active
    const bool mask0 = (kb == lo_nkb - 1);   // g0 diagonal tile
    const bool mask1 = (kb == hi_nkb - 1);   // g1 diagonal tile

    // S^T = K Q^T for both row-groups, sharing the K fragments
    f32x4 s0[4] = {}, s1[4] = {};
    __builtin_amdgcn_s_setprio(1);
#pragma unroll
    for (int ks = 0; ks < 4; ++ks)
#pragma unroll
      for (int n = 0; n < 4; ++n) {
        bf16x8 bk = *(const bf16x8*)&Kl[cur][n * 16 + l15][((ks * 4 + lg) ^ swz) * 8];
        if (act0) s0[n] = mfma_16x16x32(bk, qf0[ks], s0[n]);
        s1[n] = mfma_16x16x32(bk, qf1[ks], s1[n]);
      }
    __builtin_amdgcn_s_setprio(0);

    if (mask0) {
#pragma unroll
      for (int n = 0; n < 4; ++n)
#pragma unroll
        for (int r = 0; r < 4; ++r)
          if (kv0 + n * 16 + lg * 4 + r > myq0) s0[n][r] = -1e30f;
    }
    if (mask1) {
#pragma unroll
      for (int n = 0; n < 4; ++n)
#pragma unroll
        for (int r = 0; r < 4; ++r)
          if (kv0 + n * 16 + lg * 4 + r > myq1) s1[n][r] = -1e30f;
    }

    // per-lane online softmax in log2 domain, T13 defer-rescale, per group
    if (act0) {
      float mx = -1e30f;
#pragma unroll
      for (int n = 0; n < 4; ++n)
        mx = fmaxf(mx, fmaxf(fmaxf(s0[n][0], s0[n][1]), fmaxf(s0[n][2], s0[n][3])));
      mx = fmaxf(mx, __shfl_xor(mx, 16));
      mx = fmaxf(mx, __shfl_xor(mx, 32));
      if (!__all(mx <= m0 + 11.5f)) {
        float mn = fmaxf(m0, mx);
        float fac = exp2f(m0 - mn);
        m0 = mn; l0 *= fac;
#pragma unroll
        for (int j = 0; j < 8; ++j) {
          o0[j][0] *= fac; o0[j][1] *= fac; o0[j][2] *= fac; o0[j][3] *= fac;
        }
      }
      float rs = 0.f;
#pragma unroll
      for (int n = 0; n < 4; ++n)
#pragma unroll
        for (int r = 0; r < 4; ++r) {
          float pv = exp2f(s0[n][r] - m0);
          s0[n][r] = pv; rs += pv;
        }
      rs += __shfl_xor(rs, 16);
      rs += __shfl_xor(rs, 32);
      l0 += rs;
#pragma unroll
      for (int n = 0; n < 4; ++n) {          // P write, 16B-chunk swizzled
        ushort4 pk;
        pk.x = f2bf_trunc(s0[n][0]); pk.y = f2bf_trunc(s0[n][1]);
        pk.z = f2bf_trunc(s0[n][2]); pk.w = f2bf_trunc(s0[n][3]);
        *(ushort4*)&Pl[w][0][l15][(((2 * n + (lg >> 1)) ^ swz) << 3) + ((lg & 1) << 2)] = pk;
      }
    }
    {
      float mx = -1e30f;
#pragma unroll
      for (int n = 0; n < 4; ++n)
        mx = fmaxf(mx, fmaxf(fmaxf(s1[n][0], s1[n][1]), fmaxf(s1[n][2], s1[n][3])));
      mx = fmaxf(mx, __shfl_xor(mx, 16));
      mx = fmaxf(mx, __shfl_xor(mx, 32));
      if (!__all(mx <= m1 + 11.5f)) {
        float mn = fmaxf(m1, mx);
        float fac = exp2f(m1 - mn);
        m1 = mn; l1 *= fac;
#pragma unroll
        for (int j = 0; j < 8; ++j) {
          o1[j][0] *= fac; o1[j][1] *= fac; o1[j][2] *= fac; o1[j][3] *= fac;
        }
      }
      float rs = 0.f;
#pragma unroll
      for (int n = 0; n < 4; ++n)
#pragma unroll
        for (int r = 0; r < 4; ++r) {
          float pv = exp2f(s1[n][r] - m1);
          s1[n][r] = pv; rs += pv;
        }
      rs += __shfl_xor(rs, 16);
      rs += __shfl_xor(rs, 32);
      l1 += rs;
#pragma unroll
      for (int n = 0; n < 4; ++n) {
        ushort4 pk;
        pk.x = f2bf_trunc(s1[n][0]); pk.y = f2bf_trunc(s1[n][1]);
        pk.z = f2bf_trunc(s1[n][2]); pk.w = f2bf_trunc(s1[n][3]);
        *(ushort4*)&Pl[w][1][l15][(((2 * n + (lg >> 1)) ^ swz) << 3) + ((lg & 1) << 2)] = pk;
      }
    }
    asm volatile("s_waitcnt lgkmcnt(0)" ::: "memory");

    bf16x8 pa00, pa01;
    if (act0) {
      pa00 = *(const bf16x8*)&Pl[w][0][l15][(lg ^ swz) << 3];
      pa01 = *(const bf16x8*)&Pl[w][0][l15][((4 + lg) ^ swz) << 3];
    }
    bf16x8 pa10 = *(const bf16x8*)&Pl[w][1][l15][(lg ^ swz) << 3];
    bf16x8 pa11 = *(const bf16x8*)&Pl[w][1][l15][((4 + lg) ^ swz) << 3];

    // O^T += V^T P^T, V fragments shared by both groups
    __builtin_amdgcn_s_setprio(1);
#pragma unroll
    for (int j = 0; j < 8; ++j) {
      bf16x8 bv0 = *(const bf16x8*)&Vl[cur][j * 16 + l15][(lg ^ swz) * 8];
      bf16x8 bv1 = *(const bf16x8*)&Vl[cur][j * 16 + l15][((4 + lg) ^ swz) * 8];
      if (act0) {
        o0[j] = mfma_16x16x32(bv0, pa00, o0[j]);
        o0[j] = mfma_16x16x32(bv1, pa01, o0[j]);
      }
      o1[j] = mfma_16x16x32(bv0, pa10, o1[j]);
      o1[j] = mfma_16x16x32(bv1, pa11, o1[j]);
    }
    __builtin_amdgcn_s_setprio(0);
    cur ^= 1;
  }

  // epilogue: normalize, transpose O^T -> O via LDS (Kl for g0, Vl for g1), coalesced store
  float inv0 = 1.0f / l0, inv1 = 1.0f / l1;
  __syncthreads();                           // all waves done with Kl/Vl tiles
  unsigned short* O0 = &Kl[0][0][0];         // per-wave slot: [16][136]
  unsigned short* O1 = &Vl[0][0][0];
#pragma unroll
  for (int j = 0; j < 8; ++j) {
    ushort4 t0, t1;
    t0.x = f2bf(o0[j][0] * inv0); t0.y = f2bf(o0[j][1] * inv0);
    t0.z = f2bf(o0[j][2] * inv0); t0.w = f2bf(o0[j][3] * inv0);
    t1.x = f2bf(o1[j][0] * inv1); t1.y = f2bf(o1[j][1] * inv1);
    t1.z = f2bf(o1[j][2] * inv1); t1.w = f2bf(o1[j][3] * inv1);
    *(ushort4*)&O0[w * 2176 + l15 * 136 + j * 16 + lg * 4] = t0;
    *(ushort4*)&O1[w * 2176 + l15 * 136 + j * 16 + lg * 4] = t1;
  }
  asm volatile("s_waitcnt lgkmcnt(0)" ::: "memory");
#pragma unroll
  for (int p = 0; p < 4; ++p) {
    int row = p * 4 + lg;
    bf16x8 v0 = *(const bf16x8*)&O0[w * 2176 + row * 136 + l15 * 8];
    bf16x8 v1 = *(const bf16x8*)&O1[w * 2176 + row * 136 + l15 * 8];
    *(bf16x8*)(AO + (size_t)(lq0 + w * 16 + row) * 4096 + h * 128 + l15 * 8) = v0;
    *(bf16x8*)(AO + (size_t)(hq0 + w * 16 + row) * 4096 + h * 128 + l15 * 8) = v1;
  }
}

// ---------------- launch ----------------
extern "C" void kernel_launch(void* const* d_in, const int* in_sizes, int n_in,
                              void* d_out, int out_size, void* d_ws, size_t ws_size,
                              hipStream_t stream) {
  const float* x  = (const float*)d_in[0];
  const float* Wq = (const float*)d_in[1];
  const float* Wk = (const float*)d_in[2];
  const float* Wv = (const float*)d_in[3];
  const float* Wo = (const float*)d_in[4];
  const int*   pos = (const int*)d_in[5];
  float* out = (float*)d_out;

  char* p = (char*)d_ws;
  unsigned short* xb   = (unsigned short*)p; p += (size_t)2048 * 4096 * 2;
  unsigned short* wqkv = (unsigned short*)p; p += (size_t)6144 * 4096 * 2;  // Wq,Wk,Wv rows
  unsigned short* wob  = (unsigned short*)p; p += (size_t)4096 * 4096 * 2;
  unsigned short* qb   = (unsigned short*)p; p += (size_t)2048 * 4096 * 2;
  unsigned short* kb   = (unsigned short*)p; p += (size_t)2048 * 1024 * 2;
  unsigned short* vtb  = (unsigned short*)p; p += (size_t)1024 * 2048 * 2;
  unsigned short* aob  = (unsigned short*)p; p += (size_t)2048 * 4096 * 2;
  float2*         tab  = (float2*)p;         p += (size_t)2048 * 64 * 8;

  Conv5 ca;
  ca.x  = (const float4*)x;  ca.wq = (const float4*)Wq; ca.wk = (const float4*)Wk;
  ca.wv = (const float4*)Wv; ca.wo = (const float4*)Wo;
  ca.xb = (ushort4*)xb; ca.wqkv = (ushort4*)wqkv; ca.wob = (ushort4*)wob;
  k_conv_all<<<4096, 256, 0, stream>>>(ca);
  k_rope_table<<<512, 256, 0, stream>>>(tab);

  // merged QKV projection: C[2048][6144] split into qb / kb / vtb^T
  k_gemm64<0><<<dim3(48, 16), 256, 0, stream>>>(xb, wqkv, qb, kb, vtb, 4096);

  // 1/sqrt(128) * log2(e): softmax runs in log2 domain (exp2)
  const float scale2 = 0.08838834764831845f * 1.4426950408889634f;
  k_rope_v<32, 5><<<2048, 256, 0, stream>>>(qb, tab, pos, scale2);
  k_rope_v<8, 3><<<512, 256, 0, stream>>>(kb, tab, pos, 1.0f);

  k_attn<<<512, 256, 0, stream>>>(qb, kb, vtb, aob);

  k_gemm64<1><<<dim3(32, 16), 256, 0, stream>>>(aob, wob, out, nullptr, nullptr, 4096);
}